// Round 10
// baseline (118.377 us; speedup 1.0000x reference)
//
#include <hip/hip_runtime.h>
#include <hip/hip_bf16.h>

#define N 8192
#define D 128
#define T64 64
#define NT64 (N / T64)   // 128 tile-rows; NPAIR = 128*129/2 = 8256 pairs

typedef __attribute__((ext_vector_type(4))) int intx4;
typedef unsigned long long u64;
typedef unsigned int u32;

static __device__ inline float softplus_of(const float* __restrict__ phi) {
    float p = phi[0];
    return (p > 20.f) ? p : log1pf(__expf(p));
}

// k1: out = x + var*noise; q8[r,k] = int8(rint(16*x[r,k])); sqv[r] = ||q_r||^2
// (exact int); sqtmin[t] = min over tile t's 64 rows (u32 atomicMin vs the
// harness's 0xAA poison = 2.86e9 = +inf since real sq < 2.1e6; a zeroed ws
// would only degrade to all-slow-path = still exact); rowsum zero-init.
__global__ __launch_bounds__(256) void k1_prep(
        const float* __restrict__ x, const float* __restrict__ phi,
        const float* __restrict__ noise, float* __restrict__ out,
        signed char* __restrict__ q8, int* __restrict__ sqv,
        u32* __restrict__ sqtmin, float* __restrict__ rowsum) {
    int gid = blockIdx.x * 256 + threadIdx.x;
    int row = gid >> 4;
    int gc  = gid & 15;
    float var = softplus_of(phi);

    const float* xs = x     + (size_t)row * D + gc * 8;
    const float* ns = noise + (size_t)row * D + gc * 8;
    float4 u  = *(const float4*)xs, v  = *(const float4*)(xs + 4);
    float4 nu = *(const float4*)ns, nv = *(const float4*)(ns + 4);

    float4 o0, o1;
    o0.x = u.x + var * nu.x; o0.y = u.y + var * nu.y;
    o0.z = u.z + var * nu.z; o0.w = u.w + var * nu.w;
    o1.x = v.x + var * nv.x; o1.y = v.y + var * nv.y;
    o1.z = v.z + var * nv.z; o1.w = v.w + var * nv.w;
    float* od = out + (size_t)row * D + gc * 8;
    *(float4*)od = o0; *(float4*)(od + 4) = o1;

    float f[8] = {u.x, u.y, u.z, u.w, v.x, v.y, v.z, v.w};
    u64 pack = 0;
    int s = 0;
    #pragma unroll
    for (int k = 0; k < 8; k++) {
        float c = fminf(fmaxf(f[k] * 16.f, -127.f), 127.f);
        int q = (int)rintf(c);
        s += q * q;
        pack |= ((u64)(q & 255)) << (8 * k);
    }
    *(u64*)&q8[(size_t)row * D + gc * 8] = pack;

    #pragma unroll
    for (int m = 1; m < 16; m <<= 1) s += __shfl_xor(s, m, 64);  // row sum
    if (gc == 0) { sqv[row] = s; rowsum[row] = 0.f; }

    u32 ms = (u32)s;                                  // min over wave's 4 rows
    ms = min(ms, (u32)__shfl_xor((int)ms, 16, 64));
    ms = min(ms, (u32)__shfl_xor((int)ms, 32, 64));
    if ((threadIdx.x & 63) == 0) atomicMin(&sqtmin[row >> 6], ms);
}

static __device__ inline int triS(int t) {   // first pair index of tile-row t
    return t * 128 - ((t * (t - 1)) >> 1);
}

// k2: ONE 64x64 tile-pair per wave — straight-line code, no loops, no LDS,
// no barriers. 8256 independent waves (2064 blocks x 4). All 16 fragment
// loads issued together (single vmcnt drain), 32 MFMA, O(1) screen:
// prune iff 2*max(acc) <= sqtmin[ti]+sqtmin[tj]-Ts (every pruned term
// < 2^-30 -> IXT error < 1e-5). Exact exp2+atomic slow path only where
// flagged (the 128 diagonal tiles; off-diag flag prob ~1e-10).
__global__ __launch_bounds__(256) void k2_gram(
        const signed char* __restrict__ q8, const float* __restrict__ phi,
        const int* __restrict__ sqv, const u32* __restrict__ sqtmin,
        float* __restrict__ rowsum) {
    const int tid  = threadIdx.x;
    const int idx  = blockIdx.x * 4 + (tid >> 6);   // pair 0..8255
    const int lane = tid & 63;
    const int lrow = lane & 15;
    const int quad = lane >> 4;

    // closed-form upper-tri decode + exact integer fixup
    int ti = (int)(128.5f - sqrtf(fmaxf(128.5f * 128.5f - 2.0f * (float)idx, 0.f)));
    ti = min(max(ti, 0), 127);
    while (ti < 127 && triS(ti + 1) <= idx) ++ti;
    while (ti > 0 && triS(ti) > idx) --ti;
    const int tj = ti + (idx - triS(ti));
    const int iB = ti * T64, jB = tj * T64;

    float var = softplus_of(phi);
    const float c2 = ((-0.5f / var) * 1.4426950408889634f) * (1.f / 256.f);
    const int  Ts = (int)ceilf(30.f / (-c2));
    const int  thr = (int)sqtmin[ti] + (int)sqtmin[tj] - Ts;  // prune: 2*max<=thr

    // ---- all 16 fragment loads issued back-to-back (independent) ----
    intx4 af[4][2], bf[4][2];
    #pragma unroll
    for (int mt = 0; mt < 4; mt++) {
        const signed char* ar = q8 + (size_t)(iB + mt * 16 + lrow) * D + quad * 16;
        af[mt][0] = *(const intx4*)ar;
        af[mt][1] = *(const intx4*)(ar + 64);
    }
    #pragma unroll
    for (int nt = 0; nt < 4; nt++) {
        const signed char* br = q8 + (size_t)(jB + nt * 16 + lrow) * D + quad * 16;
        bf[nt][0] = *(const intx4*)br;
        bf[nt][1] = *(const intx4*)(br + 64);
    }

    #pragma unroll
    for (int nt = 0; nt < 4; nt++) {
        intx4 acc[4] = {};
        #pragma unroll
        for (int kk = 0; kk < 2; kk++)
            #pragma unroll
            for (int mt = 0; mt < 4; mt++)
                acc[mt] = __builtin_amdgcn_mfma_i32_16x16x64_i8(
                    af[mt][kk], bf[nt][kk], acc[mt], 0, 0, 0);

        // ---- O(1)/elem screen: lane max of acc, one ballot ----
        int lm = acc[0][0];
        #pragma unroll
        for (int mt = 0; mt < 4; mt++)
            #pragma unroll
            for (int reg = 0; reg < 4; reg++)
                lm = max(lm, acc[mt][reg]);

        if (__any(2 * lm > thr)) {
            // exact slow path (diagonal tiles + ~never off-diag)
            // C/D layout: col = lane&15, row = quad*4 + reg  [learn_hip m89]
            const int sj = sqv[jB + nt * 16 + lrow];
            float colv = 0.f;
            #pragma unroll
            for (int mt = 0; mt < 4; mt++)
                #pragma unroll
                for (int reg = 0; reg < 4; reg++) {
                    int si = sqv[iB + mt * 16 + quad * 4 + reg];
                    int d2s = si + sj - (acc[mt][reg] << 1);
                    float p = __builtin_amdgcn_exp2f((float)d2s * c2);
                    colv += p;
                    float rv = p;
                    rv += __shfl_xor(rv, 1, 64);
                    rv += __shfl_xor(rv, 2, 64);
                    rv += __shfl_xor(rv, 4, 64);
                    rv += __shfl_xor(rv, 8, 64);
                    if (lrow == 0)
                        atomicAdd(&rowsum[iB + mt * 16 + quad * 4 + reg], rv);
                }
            if (ti != tj) {  // symmetric column contribution
                colv += __shfl_xor(colv, 16, 64);
                colv += __shfl_xor(colv, 32, 64);
                if (quad == 0)
                    atomicAdd(&rowsum[jB + nt * 16 + lrow], colv);
            }
        }
    }
}

// k3: IXT = (ln N - mean_i ln rowsum[i]) / ln 2
__global__ __launch_bounds__(1024) void k3_final(
        const float* __restrict__ rowsum, float* __restrict__ out_ixt) {
    __shared__ float red[16];
    int t = threadIdx.x;
    float local = 0.f;
    for (int i = t; i < N; i += 1024) local += logf(rowsum[i]);
    #pragma unroll
    for (int m = 1; m < 64; m <<= 1) local += __shfl_xor(local, m, 64);
    if ((t & 63) == 0) red[t >> 6] = local;
    __syncthreads();
    if (t < 16) {
        float v = red[t];
        #pragma unroll
        for (int m = 1; m < 16; m <<= 1) v += __shfl_xor(v, m, 64);
        if (t == 0) {
            float kde = v / (float)N;
            out_ixt[0] = (logf((float)N) - kde) * 1.4426950408889634f;
        }
    }
}

extern "C" void kernel_launch(void* const* d_in, const int* in_sizes, int n_in,
                              void* d_out, int out_size, void* d_ws, size_t ws_size,
                              hipStream_t stream) {
    const float* x     = (const float*)d_in[0];
    const float* phi   = (const float*)d_in[1];
    const float* noise = (const float*)d_in[2];
    float* out = (float*)d_out;

    float* rowsum = (float*)d_ws;                      // N floats
    int*   sqv    = (int*)(rowsum + N);                // N ints
    u32*   sqtmin = (u32*)(sqv + N);                   // NT64 u32 (poison = +inf)
    signed char* q8 = (signed char*)(sqtmin + NT64);   // N*D int8 = 1 MB

    k1_prep<<<(N * 16) / 256, 256, 0, stream>>>(x, phi, noise, out, q8, sqv,
                                                sqtmin, rowsum);
    k2_gram<<<(NT64 * (NT64 + 1) / 2) / 4, 256, 0, stream>>>(q8, phi, sqv,
                                                             sqtmin, rowsum);
    k3_final<<<1, 1024, 0, stream>>>(rowsum, out + (size_t)N * D);
}

// Round 11
// 113.853 us; speedup vs baseline: 1.0397x; 1.0397x over previous
//
#include <hip/hip_runtime.h>
#include <hip/hip_bf16.h>

#define N 8192
#define D 128
#define T64 64
#define NT64 (N / T64)   // 128 tile-rows; NPAIR = 8256 = 2112*3 + 960*2 over 3072 waves

typedef __attribute__((ext_vector_type(4))) int intx4;
typedef unsigned long long u64;
typedef unsigned int u32;

static __device__ inline float softplus_of(const float* __restrict__ phi) {
    float p = phi[0];
    return (p > 20.f) ? p : log1pf(__expf(p));
}

// k1: out = x + var*noise; q8[r,k] = int8(rint(16*x[r,k])); sqv[r] = ||q_r||^2
// (exact int); sqtmin[t] = min over tile t's 64 rows (u32 atomicMin vs the
// harness's 0xAA poison = 2.86e9 = +inf since real sq < 2.1e6; a zeroed ws
// would only degrade to all-slow-path = still exact); rowsum zero-init.
__global__ __launch_bounds__(256) void k1_prep(
        const float* __restrict__ x, const float* __restrict__ phi,
        const float* __restrict__ noise, float* __restrict__ out,
        signed char* __restrict__ q8, int* __restrict__ sqv,
        u32* __restrict__ sqtmin, float* __restrict__ rowsum) {
    int gid = blockIdx.x * 256 + threadIdx.x;
    int row = gid >> 4;
    int gc  = gid & 15;
    float var = softplus_of(phi);

    const float* xs = x     + (size_t)row * D + gc * 8;
    const float* ns = noise + (size_t)row * D + gc * 8;
    float4 u  = *(const float4*)xs, v  = *(const float4*)(xs + 4);
    float4 nu = *(const float4*)ns, nv = *(const float4*)(ns + 4);

    float4 o0, o1;
    o0.x = u.x + var * nu.x; o0.y = u.y + var * nu.y;
    o0.z = u.z + var * nu.z; o0.w = u.w + var * nu.w;
    o1.x = v.x + var * nv.x; o1.y = v.y + var * nv.y;
    o1.z = v.z + var * nv.z; o1.w = v.w + var * nv.w;
    float* od = out + (size_t)row * D + gc * 8;
    *(float4*)od = o0; *(float4*)(od + 4) = o1;

    float f[8] = {u.x, u.y, u.z, u.w, v.x, v.y, v.z, v.w};
    u64 pack = 0;
    int s = 0;
    #pragma unroll
    for (int k = 0; k < 8; k++) {
        float c = fminf(fmaxf(f[k] * 16.f, -127.f), 127.f);
        int q = (int)rintf(c);
        s += q * q;
        pack |= ((u64)(q & 255)) << (8 * k);
    }
    *(u64*)&q8[(size_t)row * D + gc * 8] = pack;

    #pragma unroll
    for (int m = 1; m < 16; m <<= 1) s += __shfl_xor(s, m, 64);  // row sum
    if (gc == 0) { sqv[row] = s; rowsum[row] = 0.f; }

    u32 ms = (u32)s;                                  // min over wave's 4 rows
    ms = min(ms, (u32)__shfl_xor((int)ms, 16, 64));
    ms = min(ms, (u32)__shfl_xor((int)ms, 32, 64));
    if ((threadIdx.x & 63) == 0) atomicMin(&sqtmin[row >> 6], ms);
}

static __device__ inline int triS(int t) {   // first pair index of tile-row t
    return t * 128 - ((t * (t - 1)) >> 1);
}

// k2: R7 skeleton (best measured config: 768 blocks, 3 waves/EU bound, 2-3
// pairs per wave, register fragments + per-nt prefetch, no LDS/barriers)
// with the per-tile-pair O(1) screen: prune iff
//   2*max(acc) <= sqtmin[ti]+sqtmin[tj]-Ts
// (=> every exact d2s >= Ts, each pruned term < 2^-30, IXT err < 1e-5).
// Slow path (exact exp2+atomics) = the 128 diagonal tiles, ~never off-diag.
__global__ __launch_bounds__(256, 3) void k2_gram(
        const signed char* __restrict__ q8, const float* __restrict__ phi,
        const int* __restrict__ sqv, const u32* __restrict__ sqtmin,
        float* __restrict__ rowsum) {
    const int tid  = threadIdx.x;
    const int w    = blockIdx.x * 4 + (tid >> 6);
    const int lane = tid & 63;
    const int lrow = lane & 15;
    const int quad = lane >> 4;

    const int cnt = (w < 2112) ? 3 : 2;
    const int start = (w < 2112) ? 3 * w : 2 * w + 2112;

    // closed-form upper-tri decode + exact fixup (replaces the scalar loop)
    int ti = (int)(128.5f - sqrtf(fmaxf(128.5f * 128.5f - 2.0f * (float)start, 0.f)));
    ti = min(max(ti, 0), 127);
    while (ti < 127 && triS(ti + 1) <= start) ++ti;
    while (ti > 0 && triS(ti) > start) --ti;
    int tj = ti + (start - triS(ti));

    float var = softplus_of(phi);
    const float c2 = ((-0.5f / var) * 1.4426950408889634f) * (1.f / 256.f);
    const int  Ts = (int)ceilf(30.f / (-c2));

    intx4 af[4][2], bf[4][2];
    int curTi = -1;

    // prologue: B fragments for the first pair
    #pragma unroll
    for (int nt = 0; nt < 4; nt++) {
        const signed char* br = q8 + (size_t)(tj * T64 + nt * 16 + lrow) * D + quad * 16;
        bf[nt][0] = *(const intx4*)br;
        bf[nt][1] = *(const intx4*)(br + 64);
    }

    for (int r = 0; r < cnt; ++r) {
        const int iB = ti * T64, jB = tj * T64;
        const int thr = (int)sqtmin[ti] + (int)sqtmin[tj] - Ts;  // prune: 2*max<=thr

        if (ti != curTi) {
            #pragma unroll
            for (int mt = 0; mt < 4; mt++) {
                const signed char* ar = q8 + (size_t)(iB + mt * 16 + lrow) * D + quad * 16;
                af[mt][0] = *(const intx4*)ar;
                af[mt][1] = *(const intx4*)(ar + 64);
            }
            curTi = ti;
        }

        int nti = ti, ntj = tj + 1;
        if (ntj == NT64) { ++nti; ntj = nti; }
        const bool more = (r + 1 < cnt);

        #pragma unroll
        for (int nt = 0; nt < 4; nt++) {
            intx4 acc[4] = {};
            #pragma unroll
            for (int kk = 0; kk < 2; kk++)
                #pragma unroll
                for (int mt = 0; mt < 4; mt++)
                    acc[mt] = __builtin_amdgcn_mfma_i32_16x16x64_i8(
                        af[mt][kk], bf[nt][kk], acc[mt], 0, 0, 0);

            if (more) {  // prefetch next pair's bf[nt]; never drained by a barrier
                const signed char* br =
                    q8 + (size_t)(ntj * T64 + nt * 16 + lrow) * D + quad * 16;
                bf[nt][0] = *(const intx4*)br;
                bf[nt][1] = *(const intx4*)(br + 64);
            }

            // ---- O(1)/elem screen: lane max of acc, one ballot ----
            int lm = acc[0][0];
            #pragma unroll
            for (int mt = 0; mt < 4; mt++)
                #pragma unroll
                for (int reg = 0; reg < 4; reg++)
                    lm = max(lm, acc[mt][reg]);

            if (__any(2 * lm > thr)) {
                // exact slow path (diagonal tiles; off-diag flag prob ~1e-10)
                // C/D layout: col = lane&15, row = quad*4 + reg [learn_hip m89]
                const int sj = sqv[jB + nt * 16 + lrow];
                float colv = 0.f;
                #pragma unroll
                for (int mt = 0; mt < 4; mt++)
                    #pragma unroll
                    for (int reg = 0; reg < 4; reg++) {
                        int si = sqv[iB + mt * 16 + quad * 4 + reg];
                        int d2s = si + sj - (acc[mt][reg] << 1);
                        float p = __builtin_amdgcn_exp2f((float)d2s * c2);
                        colv += p;
                        float rv = p;
                        rv += __shfl_xor(rv, 1, 64);
                        rv += __shfl_xor(rv, 2, 64);
                        rv += __shfl_xor(rv, 4, 64);
                        rv += __shfl_xor(rv, 8, 64);
                        if (lrow == 0)
                            atomicAdd(&rowsum[iB + mt * 16 + quad * 4 + reg], rv);
                    }
                if (ti != tj) {  // symmetric column contribution
                    colv += __shfl_xor(colv, 16, 64);
                    colv += __shfl_xor(colv, 32, 64);
                    if (quad == 0)
                        atomicAdd(&rowsum[jB + nt * 16 + lrow], colv);
                }
            }
        }

        ti = nti; tj = ntj;
    }
}

// k3: IXT = (ln N - mean_i ln rowsum[i]) / ln 2
__global__ __launch_bounds__(1024) void k3_final(
        const float* __restrict__ rowsum, float* __restrict__ out_ixt) {
    __shared__ float red[16];
    int t = threadIdx.x;
    float local = 0.f;
    for (int i = t; i < N; i += 1024) local += logf(rowsum[i]);
    #pragma unroll
    for (int m = 1; m < 64; m <<= 1) local += __shfl_xor(local, m, 64);
    if ((t & 63) == 0) red[t >> 6] = local;
    __syncthreads();
    if (t < 16) {
        float v = red[t];
        #pragma unroll
        for (int m = 1; m < 16; m <<= 1) v += __shfl_xor(v, m, 64);
        if (t == 0) {
            float kde = v / (float)N;
            out_ixt[0] = (logf((float)N) - kde) * 1.4426950408889634f;
        }
    }
}

extern "C" void kernel_launch(void* const* d_in, const int* in_sizes, int n_in,
                              void* d_out, int out_size, void* d_ws, size_t ws_size,
                              hipStream_t stream) {
    const float* x     = (const float*)d_in[0];
    const float* phi   = (const float*)d_in[1];
    const float* noise = (const float*)d_in[2];
    float* out = (float*)d_out;

    float* rowsum = (float*)d_ws;                      // N floats
    int*   sqv    = (int*)(rowsum + N);                // N ints
    u32*   sqtmin = (u32*)(sqv + N);                   // NT64 u32 (poison = +inf)
    signed char* q8 = (signed char*)(sqtmin + NT64);   // N*D int8 = 1 MB

    k1_prep<<<(N * 16) / 256, 256, 0, stream>>>(x, phi, noise, out, q8, sqv,
                                                sqtmin, rowsum);
    k2_gram<<<768, 256, 0, stream>>>(q8, phi, sqv, sqtmin, rowsum);
    k3_final<<<1, 1024, 0, stream>>>(rowsum, out + (size_t)N * D);
}